// Round 21
// baseline (127.275 us; speedup 1.0000x reference)
//
#include <hip/hip_runtime.h>
#include <stdint.h>

#define N_BONDS 50000
#define N_EDGES 600000
#define GB 8                 // bonds per wave
#define BONDS_PER_BLOCK 32   // 4 waves
#define WIN 32               // edges per block window
#define STARTS_BLOCKS ((N_EDGES + 255) / 256)
#define PREMUL_BLOCKS ((N_BONDS + 31) / 32)
#define MAIN_BLOCKS ((N_BONDS + BONDS_PER_BLOCK - 1) / BONDS_PER_BLOCK)

typedef float f4 __attribute__((ext_vector_type(4)));
typedef unsigned short u16x4 __attribute__((ext_vector_type(4)));

__device__ __forceinline__ float bcastf(float v, int l) {
    return __builtin_bit_cast(float, __builtin_amdgcn_readlane(__builtin_bit_cast(int, v), l));
}
__device__ __forceinline__ f4 f4zero() { return (f4){0.f, 0.f, 0.f, 0.f}; }
__device__ __forceinline__ void fma4(f4& a, float s, const f4& b) {
    a.x = fmaf(s, b.x, a.x); a.y = fmaf(s, b.y, a.y);
    a.z = fmaf(s, b.z, a.z); a.w = fmaf(s, b.w, a.w);
}
__device__ __forceinline__ float bf2f(unsigned short u) {
    return __builtin_bit_cast(float, ((unsigned)u) << 16);
}
__device__ __forceinline__ unsigned short f2bf(float f) {   // RNE
    unsigned u = __builtin_bit_cast(unsigned, f);
    return (unsigned short)((u + 0x7fffu + ((u >> 16) & 1u)) >> 16);
}
__device__ __forceinline__ f4 cvt4(u16x4 u) {
    return (f4){bf2f(u.x), bf2f(u.y), bf2f(u.z), bf2f(u.w)};
}

// ---- K0: starts[] + bondKb = bf16(bond @ Ktop)  (R13-proven) ----
__global__ __launch_bounds__(256)
void prep(const int* __restrict__ edges, int* __restrict__ starts,
          const float* __restrict__ bond, const float* __restrict__ Kmat,
          unsigned short* __restrict__ bondKb) {
    __shared__ float ldsK[64 * 64];
    const int tid = threadIdx.x;

    if (blockIdx.x < STARTS_BLOCKS) {
        const int e = blockIdx.x * 256 + tid;
        if (e >= N_EDGES) return;
        const int2* edges2 = (const int2*)edges;
        const int s  = edges2[e].x;
        const int sp = (e == 0) ? -1 : edges2[e - 1].x;
        for (int b = sp + 1; b <= s; ++b) starts[b] = e;
        if (e == N_EDGES - 1)
            for (int b = s + 1; b <= N_BONDS; ++b) starts[b] = N_EDGES;
        return;
    }

    const int bid  = blockIdx.x - STARTS_BLOCKS;
    const int lane = tid & 63;
    const int wid  = tid >> 6;
    {
        const f4* K4 = (const f4*)Kmat;            // Ktop = first 1024 f4
        f4* L4 = (f4*)ldsK;
        #pragma unroll
        for (int i = 0; i < 4; ++i) L4[tid + i * 256] = K4[tid + i * 256];
    }
    __syncthreads();
    const int row0 = bid * 32 + wid * 8;
    if (row0 >= N_BONDS) return;

    float rowv[8], acc[8];
    #pragma unroll
    for (int r = 0; r < 8; ++r) {
        int ri = row0 + r; if (ri >= N_BONDS) ri = N_BONDS - 1;
        rowv[r] = bond[ri * 64 + lane];
        acc[r]  = 0.f;
    }
    #pragma unroll 4
    for (int d = 0; d < 64; ++d) {
        const float k = ldsK[d * 64 + lane];       // lane = output unit
        #pragma unroll
        for (int r = 0; r < 8; ++r)
            acc[r] = fmaf(bcastf(rowv[r], d), k, acc[r]);
    }
    #pragma unroll
    for (int r = 0; r < 8; ++r)
        if (row0 + r < N_BONDS)
            bondKb[(row0 + r) * 64 + lane] = f2bf(acc[r]);
}

// ---- K1: fused; sph staged via global_load_lds (async DMA), gathers in VGPR ----
__global__ __launch_bounds__(256, 5)
void fused_staged(const unsigned short* __restrict__ bondKb, // [N_BONDS][64] bf16
                  const float* __restrict__ sph,             // [N_EDGES][64]
                  const int*   __restrict__ edges,           // [N_EDGES][2]
                  const float* __restrict__ Kmat,            // [128][64]
                  const float* __restrict__ bias,            // [64]
                  const int*   __restrict__ starts,          // [N_BONDS+1]
                  float* __restrict__ out)                   // [N_BONDS][64]
{
    __shared__ float ldsK[64 * 64];       // 16 KB: Kbot only (G-half is premultiplied)
    __shared__ float sphb[2][WIN * 64];   // 2 x 8 KB sph window double-buffer

    const int tid  = threadIdx.x;
    const int lane = tid & 63;
    const int wid  = tid >> 6;
    const int fl   = lane & 15;   // f4-column within a 64-float row
    const int sg   = lane >> 4;   // subgroup = edge-within-quad

    {   // stage Kbot (rows 64..127 = f4 index 1024..2047)
        const f4* K4 = (const f4*)Kmat;
        f4* L4 = (f4*)ldsK;
        #pragma unroll
        for (int i = 0; i < 4; ++i) L4[tid + i * 256] = K4[1024 + tid + i * 256];
    }

    const int blkb = blockIdx.x * BONDS_PER_BLOCK;
    const int b0w  = blkb + wid * GB;

    int st[GB + 1];                               // SGPR, static-indexed only
    #pragma unroll
    for (int r = 0; r <= GB; ++r) {
        int ix = b0w + r; if (ix > N_BONDS) ix = N_BONDS;
        st[r] = __builtin_amdgcn_readfirstlane(starts[ix]);
    }
    int eblk = blkb + BONDS_PER_BLOCK; if (eblk > N_BONDS) eblk = N_BONDS;
    const int EB = __builtin_amdgcn_readfirstlane(starts[blkb]);
    const int EE = __builtin_amdgcn_readfirstlane(starts[eblk]);
    const int NW = (EE - EB + WIN - 1) / WIN;      // uniform across block

    const f4*    sph4   = (const f4*)sph;
    const int2*  edges2 = (const int2*)edges;
    const u16x4* bk4    = (const u16x4*)bondKb;

    // async stage: wave wid covers edges [W0 + 8*wid, +8) of window w -> 2 KB
    auto stage = [&](int w, int b) {
        int base = (EB + WIN * w + 8 * wid) * 16;  // f4 index of quarter start
        int a0 = base + lane;       if (a0 > N_EDGES * 16 - 1) a0 = N_EDGES * 16 - 1;
        int a1 = base + 64 + lane;  if (a1 > N_EDGES * 16 - 1) a1 = N_EDGES * 16 - 1;
        uint32_t* lp0 = (uint32_t*)&sphb[b][wid * 512];
        uint32_t* lp1 = (uint32_t*)&sphb[b][wid * 512 + 256];
        __builtin_amdgcn_global_load_lds((const uint32_t*)(sph4 + a0), lp0, 16, 0, 0);
        __builtin_amdgcn_global_load_lds((const uint32_t*)(sph4 + a1), lp1, 16, 0, 0);
    };
    auto loadwin = [&](int w) -> int2 {            // 1 coalesced idx-window load
        int e = EB + WIN * w + lane;
        if (e > N_EDGES - 1) e = N_EDGES - 1;
        return (lane < WIN) ? edges2[e] : make_int2(0, 0);
    };

    // ---- segment-walk state (absolute edge coords) ----
    float slotG[GB], slotS[GB];                    // static-indexed only
    f4 aG = f4zero(), aS = f4zero();
    int r = 0, csA = st[0], bndA = st[1];

    auto txr = [&](f4 v) -> float {                // f4 layout -> scalar layout
        v.x += __shfl_xor(v.x, 16); v.y += __shfl_xor(v.y, 16);
        v.z += __shfl_xor(v.z, 16); v.w += __shfl_xor(v.w, 16);
        v.x += __shfl_xor(v.x, 32); v.y += __shfl_xor(v.y, 32);
        v.z += __shfl_xor(v.z, 32); v.w += __shfl_xor(v.w, 32);
        const int src = lane >> 2;
        const float s0 = __shfl(v.x, src), s1 = __shfl(v.y, src);
        const float s2 = __shfl(v.z, src), s3 = __shfl(v.w, src);
        const float r01 = (lane & 1) ? s1 : s0;
        const float r23 = (lane & 1) ? s3 : s2;
        return (lane & 2) ? r23 : r01;
    };

    auto doquad = [&](int E0, f4 gv, f4 sv) {
        if (E0 + 4 <= csA) return;                 // quad before my current bond
        if (E0 >= csA && E0 + 4 <= bndA) { aG += gv; aS += sv; return; }
        const int Ee = E0 + sg;
        while (true) {                             // masked add + closes
            const float m = (Ee >= csA && Ee < bndA) ? 1.f : 0.f;
            fma4(aG, m, gv); fma4(aS, m, sv);
            if (bndA > E0 + 4) break;
            const float tG = txr(aG), tS = txr(aS);
            #pragma unroll
            for (int rr = 0; rr < GB; ++rr)
                if (rr == r) { slotG[rr] = tG; slotS[rr] = tS; }
            aG = f4zero(); aS = f4zero();
            csA = bndA;
            ++r;
            if (r >= GB) { bndA = 0x7fffffff; break; }
            #pragma unroll
            for (int rr = 2; rr <= GB; ++rr)
                if (r + 1 == rr) bndA = st[rr];
        }
    };

    // ---- prologue ----
    int2 pc = make_int2(0, 0);
    if (NW > 0) { stage(0, 0); pc = loadwin(0); }
    __syncthreads();                               // Kbot + window 0 ready

    int buf = 0;
    for (int w = 0; w < NW; ++w) {
        if (w + 1 < NW) stage(w + 1, buf ^ 1);     // async DMA, no VGPR round-trip
        int2 pn = (w + 1 < NW) ? loadwin(w + 1) : make_int2(0, 0);

        const int W0 = EB + WIN * w;

        // issue all 8 window-gathers back-to-back (one amortized stall)
        u16x4 g0 = bk4[__shfl(pc.y,  0 + sg) * 16 + fl];
        u16x4 g1 = bk4[__shfl(pc.y,  4 + sg) * 16 + fl];
        u16x4 g2 = bk4[__shfl(pc.y,  8 + sg) * 16 + fl];
        u16x4 g3 = bk4[__shfl(pc.y, 12 + sg) * 16 + fl];
        u16x4 g4 = bk4[__shfl(pc.y, 16 + sg) * 16 + fl];
        u16x4 g5 = bk4[__shfl(pc.y, 20 + sg) * 16 + fl];
        u16x4 g6 = bk4[__shfl(pc.y, 24 + sg) * 16 + fl];
        u16x4 g7 = bk4[__shfl(pc.y, 28 + sg) * 16 + fl];

        const f4* sb = (const f4*)&sphb[buf][0];   // sph from LDS: fast lgkm waits
        doquad(W0 +  0, cvt4(g0), sb[( 0 + sg) * 16 + fl]);
        doquad(W0 +  4, cvt4(g1), sb[( 4 + sg) * 16 + fl]);
        doquad(W0 +  8, cvt4(g2), sb[( 8 + sg) * 16 + fl]);
        doquad(W0 + 12, cvt4(g3), sb[(12 + sg) * 16 + fl]);
        doquad(W0 + 16, cvt4(g4), sb[(16 + sg) * 16 + fl]);
        doquad(W0 + 20, cvt4(g5), sb[(20 + sg) * 16 + fl]);
        doquad(W0 + 24, cvt4(g6), sb[(24 + sg) * 16 + fl]);
        doquad(W0 + 28, cvt4(g7), sb[(28 + sg) * 16 + fl]);

        __syncthreads();                           // drains stage(w+1); swap bufs
        buf ^= 1; pc = pn;
    }

    {   // close remaining open/empty bonds
        const float tG = txr(aG), tS = txr(aS);
        #pragma unroll
        for (int rr = 0; rr < GB; ++rr) {
            if (rr == r)     { slotG[rr] = tG;  slotS[rr] = tS; }
            else if (rr > r) { slotG[rr] = 0.f; slotS[rr] = 0.f; }
        }
    }

    // ---- epilogue: S-half matvec (Kbot) + premultiplied G-half + bias ----
    float acc[GB];
    const float bl = bias[lane];
    #pragma unroll
    for (int rr = 0; rr < GB; ++rr) acc[rr] = slotG[rr] + bl;

    #pragma unroll 4
    for (int d = 0; d < 64; ++d) {
        const float kb = ldsK[d * 64 + lane];      // 2-way bank alias: free
        #pragma unroll
        for (int rr = 0; rr < GB; ++rr)
            acc[rr] = fmaf(bcastf(slotS[rr], d), kb, acc[rr]);
    }

    #pragma unroll
    for (int rr = 0; rr < GB; ++rr)
        if (b0w + rr < N_BONDS)
            __builtin_nontemporal_store(acc[rr], &out[(b0w + rr) * 64 + lane]);
}

extern "C" void kernel_launch(void* const* d_in, const int* in_sizes, int n_in,
                              void* d_out, int out_size, void* d_ws, size_t ws_size,
                              hipStream_t stream) {
    const float* bond  = (const float*)d_in[0];
    const float* sph   = (const float*)d_in[1];
    const int*   edges = (const int*)d_in[2];
    const float* Kmat  = (const float*)d_in[3];
    const float* bias  = (const float*)d_in[4];
    float* out = (float*)d_out;

    int*            starts = (int*)d_ws;                             // 200 KB
    unsigned short* bondKb = (unsigned short*)((char*)d_ws + 262144); // 6.4 MB

    prep<<<STARTS_BLOCKS + PREMUL_BLOCKS, 256, 0, stream>>>(edges, starts,
                                                            bond, Kmat, bondKb);

    fused_staged<<<MAIN_BLOCKS, 256, 0, stream>>>(bondKb, sph, edges, Kmat,
                                                  bias, starts, out);
}

// Round 22
// 72.544 us; speedup vs baseline: 1.7544x; 1.7544x over previous
//
#include <hip/hip_runtime.h>

#define N_BONDS 50000
#define N_EDGES 600000
#define R_BONDS 4
#define THREADS 512
#define BONDS_PER_BLOCK 32   // 8 waves * 4 bonds

typedef float f4 __attribute__((ext_vector_type(4)));

__device__ __forceinline__ float bcastf(float v, int l) {
    return __builtin_bit_cast(float, __builtin_amdgcn_readlane(__builtin_bit_cast(int, v), l));
}
__device__ __forceinline__ f4 f4zero() { return (f4){0.f, 0.f, 0.f, 0.f}; }
__device__ __forceinline__ void fma4(f4& a, float s, const f4& b) {
    a.x = fmaf(s, b.x, a.x); a.y = fmaf(s, b.y, a.y);
    a.z = fmaf(s, b.z, a.z); a.w = fmaf(s, b.w, a.w);
}

// ---- kernel 1: starts[b] = lower_bound(seg, b), b in [0, N_BONDS] ----
__global__ __launch_bounds__(256)
void fill_starts(const int* __restrict__ edges, int* __restrict__ starts) {
    const int e = blockIdx.x * blockDim.x + threadIdx.x;
    if (e >= N_EDGES) return;
    const int2* edges2 = (const int2*)edges;
    const int s  = edges2[e].x;
    const int sp = (e == 0) ? -1 : edges2[e - 1].x;
    for (int b = sp + 1; b <= s; ++b) starts[b] = e;
    if (e == N_EDGES - 1)
        for (int b = s + 1; b <= N_BONDS; ++b) starts[b] = N_EDGES;
}

// ---- kernel 2: fused gather + segsum + matvec, 3-stage pipeline (R14) ----
__global__ __launch_bounds__(THREADS, 4)   // VGPR cap 128
void fused_gather_segsum_mm(const float* __restrict__ bond,   // [N_BONDS][64]
                            const float* __restrict__ sph,    // [N_EDGES][64]
                            const int*   __restrict__ edges,  // [N_EDGES][2]
                            const float* __restrict__ Kmat,   // [128][64]
                            const float* __restrict__ bias,   // [64]
                            const int*   __restrict__ starts, // [N_BONDS+1]
                            float* __restrict__ out)          // [N_BONDS][64]
{
    __shared__ float ldsK[128 * 64];   // 32 KB shared by 8 waves
    const int tid  = threadIdx.x;
    const int lane = tid & 63;
    const int wid  = tid >> 6;
    const int fl   = lane & 15;   // f4-column within a 64-float row
    const int sg   = lane >> 4;   // subgroup = edge-within-quad

    {   // stage K, coalesced 16B
        const f4* K4 = (const f4*)Kmat;
        f4*       L4 = (f4*)ldsK;
        #pragma unroll
        for (int i = 0; i < 4; ++i) L4[tid + i * THREADS] = K4[tid + i * THREADS];
    }
    __syncthreads();                                   // only barrier

    const int b0 = blockIdx.x * BONDS_PER_BLOCK + wid * R_BONDS;
    if (b0 >= N_BONDS) return;

    int st[R_BONDS + 1];                               // SGPR, static-indexed only
    #pragma unroll
    for (int r = 0; r <= R_BONDS; ++r)
        st[r] = __builtin_amdgcn_readfirstlane(starts[b0 + r]);

    const int eb    = st[0];
    const int total = st[R_BONDS] - eb;
    const int nq    = (total + 3) >> 2;                // quads

    const f4* bond4 = (const f4*)bond;
    const f4* sph4  = (const f4*)sph;

    float slotG[R_BONDS], slotS[R_BONDS];              // static-indexed only
    f4 aG = f4zero(), aS = f4zero();
    int r = 0, cs = 0, bnd = st[1] - eb;

    // cross-subgroup reduce + transpose f4 layout -> scalar layout (lane d = feat d)
    auto txr = [&](f4 v) -> float {
        v.x += __shfl_xor(v.x, 16); v.y += __shfl_xor(v.y, 16);
        v.z += __shfl_xor(v.z, 16); v.w += __shfl_xor(v.w, 16);
        v.x += __shfl_xor(v.x, 32); v.y += __shfl_xor(v.y, 32);
        v.z += __shfl_xor(v.z, 32); v.w += __shfl_xor(v.w, 32);
        const int src = lane >> 2;
        const float s0 = __shfl(v.x, src), s1 = __shfl(v.y, src);
        const float s2 = __shfl(v.z, src), s3 = __shfl(v.w, src);
        const float r01 = (lane & 1) ? s1 : s0;
        const float r23 = (lane & 1) ? s3 : s2;
        return (lane & 2) ? r23 : r01;
    };

    // boundary path: masked add, close bonds that end inside this quad
    auto slowpath = [&](int q, f4 GV, f4 SV) {
        const int qe = q + sg;
        while (true) {
            const float m = (qe >= cs && qe < bnd) ? 1.f : 0.f;
            fma4(aG, m, GV); fma4(aS, m, SV);
            if (bnd > q + 4) break;                    // bond continues past quad
            const float tG = txr(aG), tS = txr(aS);    // close bond r
            #pragma unroll
            for (int rr = 0; rr < R_BONDS; ++rr)
                if (rr == r) { slotG[rr] = tG; slotS[rr] = tS; }
            aG = f4zero(); aS = f4zero();
            cs = bnd;
            ++r;
            if (r >= R_BONDS) { bnd = 0x7fffffff; break; }
            #pragma unroll
            for (int rr = 2; rr <= R_BONDS; ++rr)
                if (r + 1 == rr) bnd = st[rr] - eb;
        }
    };

    // stage 1: subgroup-uniform index load (prefetched 8 quads ahead; off the chain)
    auto loadIdx = [&](int Q) -> int {
        if (Q >= nq) return 0;                         // uniform guard: no load
        int e = 4 * Q + sg;
        e = (e < total) ? e : total - 1;
        return edges[2 * (eb + e) + 1];                // 4 dwords/wave, 16x replicated
    };
    // stage 2: data loads from a ready index register
    auto issData = [&](int nbr, int Q, f4& GV, f4& SV) {
        int e = 4 * Q + sg;
        e = (e < total) ? e : total - 1;
        GV = bond4[nbr * 16 + fl];
        SV = sph4[(eb + e) * 16 + fl];
    };
    // stage 3: accumulate (wave-uniform segment logic)
    auto accq = [&](int Q, f4 GV, f4 SV) {
        const int q_ = Q * 4;
        if (q_ + 4 <= bnd) { aG += GV; aS += SV; }
        else slowpath(q_, GV, SV);
    };

    if (nq > 0) {
        f4 gA = f4zero(), sA = f4zero(), gB = f4zero(), sB = f4zero();
        f4 gC = f4zero(), sC = f4zero(), gD = f4zero(), sD = f4zero();

        int i0 = loadIdx(0), i1 = loadIdx(1), i2 = loadIdx(2), i3 = loadIdx(3);
        int j0 = loadIdx(4), j1 = loadIdx(5), j2 = loadIdx(6), j3 = loadIdx(7);

        issData(i0, 0, gA, sA);
        if (1 < nq) issData(i1, 1, gB, sB);
        if (2 < nq) issData(i2, 2, gC, sC);
        if (3 < nq) issData(i3, 3, gD, sD);
        i0 = j0; i1 = j1; i2 = j2; i3 = j3;
        j0 = loadIdx(8); j1 = loadIdx(9); j2 = loadIdx(10); j3 = loadIdx(11);

        for (int q = 0; q < nq; q += 4) {
            accq(q + 0, gA, sA);
            if (q + 4 < nq) issData(i0, q + 4, gA, sA);
            if (q + 1 < nq) { accq(q + 1, gB, sB); if (q + 5 < nq) issData(i1, q + 5, gB, sB); }
            if (q + 2 < nq) { accq(q + 2, gC, sC); if (q + 6 < nq) issData(i2, q + 6, gC, sC); }
            if (q + 3 < nq) { accq(q + 3, gD, sD); if (q + 7 < nq) issData(i3, q + 7, gD, sD); }
            i0 = j0; i1 = j1; i2 = j2; i3 = j3;
            j0 = loadIdx(q + 12); j1 = loadIdx(q + 13);
            j2 = loadIdx(q + 14); j3 = loadIdx(q + 15);
        }
    }

    {   // close remaining open/empty bonds
        const float tG = txr(aG), tS = txr(aS);
        #pragma unroll
        for (int rr = 0; rr < R_BONDS; ++rr) {
            if (rr == r)     { slotG[rr] = tG;  slotS[rr] = tS; }
            else if (rr > r) { slotG[rr] = 0.f; slotS[rr] = 0.f; }
        }
    }

    // ---- deferred matvec: 4 bonds amortize each LDS K read ----
    float acc[R_BONDS];
    const float bl = bias[lane];
    #pragma unroll
    for (int rr = 0; rr < R_BONDS; ++rr) acc[rr] = bl;

    #pragma unroll 4
    for (int d = 0; d < 64; ++d) {
        const float kt = ldsK[d * 64 + lane];          // 2-way bank alias: free
        const float kb = ldsK[(64 + d) * 64 + lane];
        #pragma unroll
        for (int rr = 0; rr < R_BONDS; ++rr) {
            acc[rr] = fmaf(bcastf(slotG[rr], d), kt, acc[rr]);
            acc[rr] = fmaf(bcastf(slotS[rr], d), kb, acc[rr]);
        }
    }

    #pragma unroll
    for (int rr = 0; rr < R_BONDS; ++rr)
        if (b0 + rr < N_BONDS)
            __builtin_nontemporal_store(acc[rr], &out[(b0 + rr) * 64 + lane]);
}

extern "C" void kernel_launch(void* const* d_in, const int* in_sizes, int n_in,
                              void* d_out, int out_size, void* d_ws, size_t ws_size,
                              hipStream_t stream) {
    const float* bond  = (const float*)d_in[0];
    const float* sph   = (const float*)d_in[1];
    const int*   edges = (const int*)d_in[2];
    const float* Kmat  = (const float*)d_in[3];
    const float* bias  = (const float*)d_in[4];
    float* out  = (float*)d_out;
    int* starts = (int*)d_ws;                          // (N_BONDS+1)*4 = 200 KB

    fill_starts<<<(N_EDGES + 255) / 256, 256, 0, stream>>>(edges, starts);

    const int nblocks = (N_BONDS + BONDS_PER_BLOCK - 1) / BONDS_PER_BLOCK;
    fused_gather_segsum_mm<<<nblocks, THREADS, 0, stream>>>(bond, sph, edges, Kmat,
                                                            bias, starts, out);
}